// Round 5
// baseline (1174.436 us; speedup 1.0000x reference)
//
#include <hip/hip_runtime.h>
#include <hip/hip_bf16.h>

#define NN 50000
#define NE 800000
#define F 128     // input feature dim (= K)
#define HD 128    // output dim = H*DH (= N)
#define H 4

typedef __attribute__((ext_vector_type(4))) float f32x4;
typedef __attribute__((ext_vector_type(8))) __bf16 bf16x8;

// ---------- helpers ----------

// mish(x) = x * tanh(softplus(x)) = x * (u-1)/(u+1), u = (1+e^x)^2
__device__ __forceinline__ float mish_f(float x) {
    if (x > 30.f) return x;
    float t = __expf(x);
    float u = 1.f + t;
    u = u * u;
    return x * (u - 1.f) * __builtin_amdgcn_rcpf(u + 1.f);
}

__device__ __forceinline__ unsigned f32_to_bf16(float x) {
    unsigned u = __float_as_uint(x);
    u += 0x7FFFu + ((u >> 16) & 1u);
    return u >> 16;
}

// first index r in [0, n] with a[r] >= v
__device__ __forceinline__ int lower_bound_u(const unsigned* a, int n, unsigned v) {
    int lo = 0, hi = n;
    while (lo < hi) { int mid = (lo + hi) >> 1; if (a[mid] < v) lo = mid + 1; else hi = mid; }
    return lo;
}

// ---------- prep: W f32[128k x 128n] -> bf16 fragment-ordered ----------
__global__ __launch_bounds__(256) void prep_w(
    const float* __restrict__ W0, const float* __restrict__ W1,
    const float* __restrict__ W2, uint4* __restrict__ O)
{
    int b = blockIdx.x;
    const float* W = (b == 0) ? W0 : (b == 1) ? W1 : W2;
    uint4* out = O + b * 2048;
    for (int c = threadIdx.x; c < 2048; c += 256) {
        int fn = c >> 8, ks = (c >> 6) & 3, lane = c & 63;
        int lgp = lane >> 4, l15 = lane & 15;
        int col = fn * 16 + l15, k0 = ks * 32 + lgp * 8;
        unsigned u[4];
        #pragma unroll
        for (int i = 0; i < 4; ++i) {
            float a = W[(k0 + 2 * i) * 128 + col];
            float bb = W[(k0 + 2 * i + 1) * 128 + col];
            u[i] = f32_to_bf16(a) | (f32_to_bf16(bb) << 16);
        }
        out[c] = make_uint4(u[0], u[1], u[2], u[3]);
    }
}

// ---------- node projection GEMM (B from fragment-ordered global) ----------
__global__ __launch_bounds__(256, 4) void proj_gemm(
    const float* __restrict__ X, const bf16x8* __restrict__ Wf,
    const float* __restrict__ bias, int M, float* __restrict__ Y)
{
    __shared__ __align__(16) char ldsA[32768];
    const int t = threadIdx.x;
    const int lane = t & 63;
    const int wid = t >> 6;
    const size_t rowbase = (size_t)blockIdx.x * 128;

    #pragma unroll
    for (int i = 0; i < 8; ++i) {
        int c = i * 256 + t;
        int row = c >> 4, cc = c & 15;
        size_t e = rowbase + row;
        uint4 p = make_uint4(0, 0, 0, 0);
        if (e < (size_t)M) {
            const float4* src = (const float4*)(X + e * F + cc * 8);
            float4 f0 = src[0], f1 = src[1];
            p.x = f32_to_bf16(f0.x) | (f32_to_bf16(f0.y) << 16);
            p.y = f32_to_bf16(f0.z) | (f32_to_bf16(f0.w) << 16);
            p.z = f32_to_bf16(f1.x) | (f32_to_bf16(f1.y) << 16);
            p.w = f32_to_bf16(f1.z) | (f32_to_bf16(f1.w) << 16);
        }
        unsigned byte = (unsigned)(row * 256 + cc * 16);
        byte ^= (unsigned)((row & 7) << 4);
        *(uint4*)(ldsA + byte) = p;
    }

    const int wr = wid >> 1, wc = wid & 1;
    const int l15 = lane & 15, lgp = lane >> 4;
    f32x4 acc[4][4];
    #pragma unroll
    for (int n = 0; n < 4; ++n) {
        float bv = bias[wc * 64 + n * 16 + l15];
        #pragma unroll
        for (int m = 0; m < 4; ++m) {
            acc[m][n][0] = bv; acc[m][n][1] = bv;
            acc[m][n][2] = bv; acc[m][n][3] = bv;
        }
    }
    __syncthreads();

    #pragma unroll
    for (int ks = 0; ks < 4; ++ks) {
        const int kb = ks * 64 + lgp * 16;
        bf16x8 af[4], bfr[4];
        #pragma unroll
        for (int m = 0; m < 4; ++m) {
            int row = wr * 64 + m * 16 + l15;
            unsigned byte = ((unsigned)(row * 256 + kb)) ^ ((row & 7) << 4);
            af[m] = *(const bf16x8*)(ldsA + byte);
        }
        #pragma unroll
        for (int n = 0; n < 4; ++n)
            bfr[n] = Wf[((wc * 4 + n) * 4 + ks) * 64 + lane];
        #pragma unroll
        for (int m = 0; m < 4; ++m)
            #pragma unroll
            for (int n = 0; n < 4; ++n)
                acc[m][n] = __builtin_amdgcn_mfma_f32_16x16x32_bf16(
                    af[m], bfr[n], acc[m][n], 0, 0, 0);
    }

    #pragma unroll
    for (int m = 0; m < 4; ++m)
        #pragma unroll
        for (int j = 0; j < 4; ++j) {
            int row = wr * 64 + m * 16 + lgp * 4 + j;
            size_t e = rowbase + row;
            if (e >= (size_t)M) continue;
            float* dst = Y + e * HD + wc * 64 + l15;
            #pragma unroll
            for (int n = 0; n < 4; ++n)
                dst[n * 16] = acc[m][n][j];
        }
}

// ---------- CSR build ----------
__global__ __launch_bounds__(256) void hist_kernel(
    const int* __restrict__ receivers, unsigned* __restrict__ cnt)
{
    int i = blockIdx.x * 256 + threadIdx.x;
    if (i < NE) atomicAdd(&cnt[receivers[i]], 1u);
}

__global__ __launch_bounds__(1024) void scan_kernel(
    const unsigned* __restrict__ cnt, unsigned* __restrict__ rowptr)
{
    __shared__ unsigned part[1024];
    const int t = threadIdx.x;
    const int C = (NN + 1023) / 1024;
    int base = t * C;
    unsigned s = 0;
    for (int i = 0; i < C; ++i) {
        int idx = base + i;
        if (idx < NN) s += cnt[idx];
    }
    part[t] = s;
    __syncthreads();
    for (int off = 1; off < 1024; off <<= 1) {
        unsigned v = (t >= off) ? part[t - off] : 0u;
        __syncthreads();
        if (t >= off) part[t] += v;
        __syncthreads();
    }
    unsigned run = part[t] - s;
    for (int i = 0; i < C; ++i) {
        int idx = base + i;
        if (idx < NN) { rowptr[idx] = run; run += cnt[idx]; }
    }
    if (t == 1023) rowptr[NN] = run;
}

__global__ __launch_bounds__(256) void scatter_kernel(
    const int* __restrict__ receivers, const unsigned* __restrict__ rowptr,
    unsigned* __restrict__ cnt2, unsigned* __restrict__ perm)
{
    int i = blockIdx.x * 256 + threadIdx.x;
    if (i >= NE) return;
    int r = receivers[i];
    unsigned pos = rowptr[r] + atomicAdd(&cnt2[r], 1u);
    perm[pos] = (unsigned)i;
}

// ---------- fused edge GEMM + segment softmax + aggregation ----------
// Block k owns receivers whose first edge is in perm-window [128k, 128(k+1)).
// It loops over their edges in 128-row chunks (online softmax across chunks).
__global__ __launch_bounds__(256, 4) void fused_edge(
    const float* __restrict__ edges, const bf16x8* __restrict__ Wf,
    const float* __restrict__ bias,
    const float* __restrict__ attw, const float* __restrict__ attb,
    const int* __restrict__ senders,
    const float* __restrict__ S, const float* __restrict__ Rm,
    const unsigned* __restrict__ rowptr, const unsigned* __restrict__ perm,
    float* __restrict__ out)
{
    __shared__ __align__(16) char ldsA[32768];    // A-stage, then EA tile (bf16)
    __shared__ float sLogit[128][4];              // logits -> exp -> weights
    __shared__ int   sRowRcv[128];                // (r<<2)|cont<<1|open
    __shared__ int   sEid[128];
    __shared__ float sAccRun[128];                // straddler col state
    __shared__ float sMrun[4], sDrun[4], sMprev[4], sDprev[4];
    __shared__ float sScale[4], sContInv[4];
    __shared__ int   sR2[2];

    const int t = threadIdx.x;
    const int lane = t & 63;
    const int wid = t >> 6;
    const int wr = wid >> 1, wc = wid & 1;
    const int l15 = lane & 15, lgp = lane >> 4;

    if (t == 0) {
        sR2[0] = lower_bound_u(rowptr, NN + 1, 128u * blockIdx.x);
        sR2[1] = lower_bound_u(rowptr, NN + 1, 128u * (blockIdx.x + 1));
    }
    if (t < 4) { sMrun[t] = -3.402823466e+38f; sDrun[t] = 0.f; }
    __syncthreads();
    const int rlo = sR2[0], rhi = sR2[1];
    if (rlo >= rhi) return;
    const unsigned e_beg = rowptr[rlo], e_end = rowptr[rhi];
    if (e_beg >= e_end) return;
    const int nR = rhi - rlo;

    const float aw0 = attw[l15];
    const float aw1 = attw[l15 + 16];
    const float ab0 = attb[0];

    for (unsigned c0 = e_beg; c0 < e_end; c0 += 128) {
        const unsigned c1 = (c0 + 128 < e_end) ? c0 + 128 : e_end;
        const int nrows = (int)(c1 - c0);

        // snapshot straddler scalar state (race-free read in phase 1)
        if (t < 4) { sMprev[t] = sMrun[t]; sDprev[t] = sDrun[t]; }

        // ---- stage A: gathered edge rows -> bf16, XOR-swizzled ----
        #pragma unroll
        for (int i = 0; i < 8; ++i) {
            int c = i * 256 + t;
            int row = c >> 4, cc = c & 15;
            unsigned j = c0 + (unsigned)row;
            uint4 p = make_uint4(0, 0, 0, 0);
            if (j < c1) {
                unsigned e = perm[j];
                if (cc == 0) sEid[row] = (int)e;
                const float4* src = (const float4*)(edges + (size_t)e * F + cc * 8);
                float4 f0 = src[0], f1 = src[1];
                p.x = f32_to_bf16(f0.x) | (f32_to_bf16(f0.y) << 16);
                p.y = f32_to_bf16(f0.z) | (f32_to_bf16(f0.w) << 16);
                p.z = f32_to_bf16(f1.x) | (f32_to_bf16(f1.y) << 16);
                p.w = f32_to_bf16(f1.z) | (f32_to_bf16(f1.w) << 16);
            }
            unsigned byte = (unsigned)(row * 256 + cc * 16);
            byte ^= (unsigned)((row & 7) << 4);
            *(uint4*)(ldsA + byte) = p;
        }
        // ---- row -> receiver map (+flags) ----
        for (int rr = rlo + t; rr < rhi; rr += 256) {
            unsigned ra = rowptr[rr], rb = rowptr[rr + 1];
            unsigned a = ra > c0 ? ra : c0;
            unsigned b = rb < c1 ? rb : c1;
            if (a >= b) continue;
            int tag = (rr << 2) | ((ra < c0) ? 2 : 0) | ((rb > c1) ? 1 : 0);
            for (unsigned j = a; j < b; ++j) sRowRcv[j - c0] = tag;
        }

        f32x4 acc[4][4];
        #pragma unroll
        for (int n = 0; n < 4; ++n) {
            float bv = bias[wc * 64 + n * 16 + l15];
            #pragma unroll
            for (int m = 0; m < 4; ++m) {
                acc[m][n][0] = bv; acc[m][n][1] = bv;
                acc[m][n][2] = bv; acc[m][n][3] = bv;
            }
        }
        __syncthreads();

        // ---- MFMA ----
        #pragma unroll
        for (int ks = 0; ks < 4; ++ks) {
            const int kb = ks * 64 + lgp * 16;
            bf16x8 af[4], bfr[4];
            #pragma unroll
            for (int m = 0; m < 4; ++m) {
                int row = wr * 64 + m * 16 + l15;
                unsigned byte = ((unsigned)(row * 256 + kb)) ^ ((row & 7) << 4);
                af[m] = *(const bf16x8*)(ldsA + byte);
            }
            #pragma unroll
            for (int n = 0; n < 4; ++n)
                bfr[n] = Wf[((wc * 4 + n) * 4 + ks) * 64 + lane];
            #pragma unroll
            for (int m = 0; m < 4; ++m)
                #pragma unroll
                for (int n = 0; n < 4; ++n)
                    acc[m][n] = __builtin_amdgcn_mfma_f32_16x16x32_bf16(
                        af[m], bfr[n], acc[m][n], 0, 0, 0);
        }
        __syncthreads();   // all ldsA reads done

        // ---- tail: EA -> LDS (swizzled), logits -> sLogit ----
        #pragma unroll
        for (int m = 0; m < 4; ++m) {
            #pragma unroll
            for (int j2 = 0; j2 < 4; ++j2) {
                int row = wr * 64 + m * 16 + lgp * 4 + j2;
                if (row < nrows) {
                    int e = sEid[row];
                    int rcv = sRowRcv[row] >> 2;
                    int snd = senders[e];
                    const float* Srow = S + (size_t)snd * HD + wc * 64 + l15;
                    const float* Rrow = Rm + (size_t)rcv * HD + wc * 64 + l15;
                    float ea0 = acc[m][0][j2] + Srow[0];
                    float ea1 = acc[m][1][j2] + Srow[16];
                    float ea2 = acc[m][2][j2] + Srow[32];
                    float ea3 = acc[m][3][j2] + Srow[48];
                    uint2 pk;
                    pk.x = f32_to_bf16(ea0) | (f32_to_bf16(ea1) << 16);
                    pk.y = f32_to_bf16(ea2) | (f32_to_bf16(ea3) << 16);
                    int idx = wc * 16 + (l15 ^ lgp);   // (row>>2)&3 == lgp
                    *(uint2*)(ldsA + row * 256 + idx * 8) = pk;
                    float p0 = mish_f(ea0 + Rrow[0])  * aw0
                             + mish_f(ea1 + Rrow[16]) * aw1;
                    float p1 = mish_f(ea2 + Rrow[32]) * aw0
                             + mish_f(ea3 + Rrow[48]) * aw1;
                    p0 += __shfl_xor(p0, 1); p1 += __shfl_xor(p1, 1);
                    p0 += __shfl_xor(p0, 2); p1 += __shfl_xor(p1, 2);
                    p0 += __shfl_xor(p0, 4); p1 += __shfl_xor(p1, 4);
                    p0 += __shfl_xor(p0, 8); p1 += __shfl_xor(p1, 8);
                    if (l15 == 0) {
                        sLogit[row][wc * 2 + 0] = p0 + ab0;
                        sLogit[row][wc * 2 + 1] = p1 + ab0;
                    }
                }
            }
        }
        __syncthreads();

        // ---- phase 1: per-(receiver, head) softmax stats; sLogit -> weights ----
        for (int idx = t; idx < nR * 4; idx += 256) {
            int rr = rlo + (idx >> 2), h = idx & 3;
            unsigned ra = rowptr[rr], rb = rowptr[rr + 1];
            unsigned a = ra > c0 ? ra : c0;
            unsigned b = rb < c1 ? rb : c1;
            if (a >= b) continue;
            bool cont = ra < c0, open = rb > c1;
            float mx = -3.402823466e+38f;
            for (unsigned j = a; j < b; ++j) mx = fmaxf(mx, sLogit[j - c0][h]);
            float mb = cont ? fmaxf(sMprev[h], mx) : mx;
            float d = 0.f;
            for (unsigned j = a; j < b; ++j) {
                float ex = __expf(sLogit[j - c0][h] - mb);
                sLogit[j - c0][h] = ex;
                d += ex;
            }
            if (cont) {
                float sc = __expf(sMprev[h] - mb);
                sScale[h] = sc;
                d += sDprev[h] * sc;
            }
            if (open) { sMrun[h] = mb; sDrun[h] = d; }
            else if (cont) { sContInv[h] = 1.f / d; }
            else {
                float inv = 1.f / d;
                for (unsigned j = a; j < b; ++j) sLogit[j - c0][h] *= inv;
            }
        }
        __syncthreads();

        // ---- phase 3: column-parallel aggregation, write rows once ----
        if (t < 128) {
            const int c = t, h = c >> 5;
            const int wcol = c >> 6, l15c = c & 15, sub = (c >> 4) & 3;
            float a2 = 0.f;
            int cur = sRowRcv[0];
            #define FLUSH(TAG) do { int rr_ = (TAG) >> 2;                    \
                bool ct_ = (TAG) & 2, op_ = (TAG) & 1; float v_ = a2;        \
                if (ct_) v_ += sAccRun[c] * sScale[h];                       \
                if (op_) sAccRun[c] = v_;                                    \
                else { if (ct_) v_ *= sContInv[h];                           \
                       out[(size_t)rr_ * HD + c] = v_; } } while (0)
            for (int row = 0; row < nrows; ++row) {
                int tag = sRowRcv[row];
                if (tag != cur) { FLUSH(cur); a2 = 0.f; cur = tag; }
                int idx = wcol * 16 + (l15c ^ ((row >> 2) & 3));
                unsigned short us = *(const unsigned short*)
                    (ldsA + row * 256 + idx * 8 + sub * 2);
                a2 += sLogit[row][h] * __uint_as_float(((unsigned)us) << 16);
            }
            FLUSH(cur);
            #undef FLUSH
        }
        __syncthreads();   // protect ldsA/state before next chunk
    }
}

// ---------- host ----------
extern "C" void kernel_launch(void* const* d_in, const int* in_sizes, int n_in,
                              void* d_out, int out_size, void* d_ws, size_t ws_size,
                              hipStream_t stream) {
    const float* nodes = (const float*)d_in[0];
    const float* edges = (const float*)d_in[1];
    const float* Ws_k  = (const float*)d_in[2];
    const float* Ws_b  = (const float*)d_in[3];
    const float* Wr_k  = (const float*)d_in[4];
    const float* Wr_b  = (const float*)d_in[5];
    const float* We_k  = (const float*)d_in[6];
    const float* We_b  = (const float*)d_in[7];
    const float* attw  = (const float*)d_in[8];
    const float* attb  = (const float*)d_in[9];
    const int* senders   = (const int*)d_in[10];
    const int* receivers = (const int*)d_in[11];
    float* out = (float*)d_out;

    char* ws = (char*)d_ws;
    const size_t S_OFF    = 0;                 // 25,600,000
    const size_t R_OFF    = 25600000;          // 25,600,000
    const size_t CNT_OFF  = 51200000;          // 200,000
    const size_t CNT2_OFF = 51400000;          // 200,000
    const size_t RP_OFF   = 51600000;          // 200,004
    const size_t PERM_OFF = 51800008;          // 3,200,000
    const size_t WF_OFF   = 55000016;          // 98,304

    float*    S      = (float*)(ws + S_OFF);
    float*    Rr     = (float*)(ws + R_OFF);
    unsigned* cnt    = (unsigned*)(ws + CNT_OFF);
    unsigned* cnt2   = (unsigned*)(ws + CNT2_OFF);
    unsigned* rowptr = (unsigned*)(ws + RP_OFF);
    unsigned* perm   = (unsigned*)(ws + PERM_OFF);
    uint4*    Wf     = (uint4*)(ws + WF_OFF);
    (void)ws_size;

    // weights -> bf16 fragment order (Ws, Wr, We)
    prep_w<<<3, 256, 0, stream>>>(Ws_k, Wr_k, We_k, Wf);

    // CSR build
    hipMemsetAsync(ws + CNT_OFF, 0, 400000, stream);   // cnt + cnt2
    hist_kernel<<<(NE + 255) / 256, 256, 0, stream>>>(receivers, cnt);
    scan_kernel<<<1, 1024, 0, stream>>>(cnt, rowptr);
    scatter_kernel<<<(NE + 255) / 256, 256, 0, stream>>>(receivers, rowptr, cnt2, perm);

    // node projections
    proj_gemm<<<(NN + 127) / 128, 256, 0, stream>>>(
        nodes, (const bf16x8*)(Wf), Ws_b, NN, S);
    proj_gemm<<<(NN + 127) / 128, 256, 0, stream>>>(
        nodes, (const bf16x8*)(Wf + 2048), Wr_b, NN, Rr);

    // zero output (covers zero-degree receivers)
    hipMemsetAsync(out, 0, (size_t)NN * HD * sizeof(float), stream);

    // fused edge GEMM + segment softmax + aggregation
    fused_edge<<<NE / 128, 256, 0, stream>>>(
        edges, (const bf16x8*)(Wf + 4096), We_b,
        attw, attb, senders, S, Rr, rowptr, perm, out);
}

// Round 6
// 552.664 us; speedup vs baseline: 2.1250x; 2.1250x over previous
//
#include <hip/hip_runtime.h>
#include <hip/hip_bf16.h>

#define NN 50000
#define NE 800000
#define F 128     // input feature dim (= K)
#define HD 128    // output dim = H*DH (= N)
#define H 4

typedef __attribute__((ext_vector_type(4))) float f32x4;
typedef __attribute__((ext_vector_type(8))) __bf16 bf16x8;

// ---------- helpers ----------

// mish(x) = x * tanh(softplus(x)) = x * (u-1)/(u+1), u = (1+e^x)^2
__device__ __forceinline__ float mish_f(float x) {
    if (x > 30.f) return x;
    float t = __expf(x);
    float u = 1.f + t;
    u = u * u;
    return x * (u - 1.f) * __builtin_amdgcn_rcpf(u + 1.f);
}

__device__ __forceinline__ unsigned f32_to_bf16(float x) {
    unsigned u = __float_as_uint(x);
    u += 0x7FFFu + ((u >> 16) & 1u);
    return u >> 16;
}
__device__ __forceinline__ float bf16lo_to_f32(unsigned p) {
    return __uint_as_float((p & 0xFFFFu) << 16);
}
__device__ __forceinline__ float bf16hi_to_f32(unsigned p) {
    return __uint_as_float(p & 0xFFFF0000u);
}

// ---------- prep: W f32[128k x 128n] -> bf16 fragment-ordered ----------
__global__ __launch_bounds__(256) void prep_w(
    const float* __restrict__ W0, const float* __restrict__ W1,
    const float* __restrict__ W2, uint4* __restrict__ O)
{
    int b = blockIdx.x;
    const float* W = (b == 0) ? W0 : (b == 1) ? W1 : W2;
    uint4* out = O + b * 2048;
    for (int c = threadIdx.x; c < 2048; c += 256) {
        int fn = c >> 8, ks = (c >> 6) & 3, lane = c & 63;
        int lgp = lane >> 4, l15 = lane & 15;
        int col = fn * 16 + l15, k0 = ks * 32 + lgp * 8;
        unsigned u[4];
        #pragma unroll
        for (int i = 0; i < 4; ++i) {
            float a = W[(k0 + 2 * i) * 128 + col];
            float bb = W[(k0 + 2 * i + 1) * 128 + col];
            u[i] = f32_to_bf16(a) | (f32_to_bf16(bb) << 16);
        }
        out[c] = make_uint4(u[0], u[1], u[2], u[3]);
    }
}

// ---------- CSR build ----------
__global__ __launch_bounds__(256) void hist_kernel(
    const int* __restrict__ receivers, unsigned* __restrict__ cnt)
{
    int i = blockIdx.x * 256 + threadIdx.x;
    if (i < NE) atomicAdd(&cnt[receivers[i]], 1u);
}

__global__ __launch_bounds__(1024) void scan_kernel(
    const unsigned* __restrict__ cnt, unsigned* __restrict__ rowptr)
{
    __shared__ unsigned part[1024];
    const int t = threadIdx.x;
    const int C = (NN + 1023) / 1024;
    int base = t * C;
    unsigned s = 0;
    for (int i = 0; i < C; ++i) {
        int idx = base + i;
        if (idx < NN) s += cnt[idx];
    }
    part[t] = s;
    __syncthreads();
    for (int off = 1; off < 1024; off <<= 1) {
        unsigned v = (t >= off) ? part[t - off] : 0u;
        __syncthreads();
        if (t >= off) part[t] += v;
        __syncthreads();
    }
    unsigned run = part[t] - s;
    for (int i = 0; i < C; ++i) {
        int idx = base + i;
        if (idx < NN) { rowptr[idx] = run; run += cnt[idx]; }
    }
    if (t == 1023) rowptr[NN] = run;
}

// scatter + inverse map jof: edge e lands at perm position jof[e]
__global__ __launch_bounds__(256) void scatter_kernel(
    const int* __restrict__ receivers, const unsigned* __restrict__ rowptr,
    unsigned* __restrict__ cnt2, unsigned* __restrict__ jof)
{
    int i = blockIdx.x * 256 + threadIdx.x;
    if (i >= NE) return;
    int r = receivers[i];
    unsigned pos = rowptr[r] + atomicAdd(&cnt2[r], 1u);
    jof[i] = pos;
}

// ---------- both node projections in one kernel ----------
// Sp/Rp layout: node row = 32 float4; float4 at idx=wc*16+l15 holds cols
// {wc*64 + n*16 + l15 : n=0..3}  (matches MFMA fragment cols)
__global__ __launch_bounds__(256, 4) void proj_both(
    const float* __restrict__ X,
    const bf16x8* __restrict__ Wf0, const bf16x8* __restrict__ Wf1,
    const float* __restrict__ b0, const float* __restrict__ b1,
    int M, float4* __restrict__ Sp, float4* __restrict__ Rp)
{
    __shared__ __align__(16) char ldsA[32768];
    const int t = threadIdx.x;
    const int lane = t & 63;
    const int wid = t >> 6;
    const int wr = wid >> 1, wc = wid & 1;
    const int l15 = lane & 15, lgp = lane >> 4;
    const size_t rowbase = (size_t)blockIdx.x * 128;

    #pragma unroll
    for (int i = 0; i < 8; ++i) {
        int c = i * 256 + t;
        int row = c >> 4, cc = c & 15;
        size_t e = rowbase + row;
        uint4 p = make_uint4(0, 0, 0, 0);
        if (e < (size_t)M) {
            const float4* src = (const float4*)(X + e * F + cc * 8);
            float4 f0 = src[0], f1 = src[1];
            p.x = f32_to_bf16(f0.x) | (f32_to_bf16(f0.y) << 16);
            p.y = f32_to_bf16(f0.z) | (f32_to_bf16(f0.w) << 16);
            p.z = f32_to_bf16(f1.x) | (f32_to_bf16(f1.y) << 16);
            p.w = f32_to_bf16(f1.z) | (f32_to_bf16(f1.w) << 16);
        }
        unsigned byte = (unsigned)(row * 256 + cc * 16);
        byte ^= (unsigned)((row & 7) << 4);
        *(uint4*)(ldsA + byte) = p;
    }
    __syncthreads();

    #pragma unroll
    for (int pass = 0; pass < 2; ++pass) {
        const bf16x8* Wf = pass ? Wf1 : Wf0;
        const float* bias = pass ? b1 : b0;
        float4* Y = pass ? Rp : Sp;

        f32x4 acc[4][4];
        #pragma unroll
        for (int n = 0; n < 4; ++n) {
            float bv = bias[wc * 64 + n * 16 + l15];
            #pragma unroll
            for (int m = 0; m < 4; ++m) {
                acc[m][n][0] = bv; acc[m][n][1] = bv;
                acc[m][n][2] = bv; acc[m][n][3] = bv;
            }
        }
        #pragma unroll
        for (int ks = 0; ks < 4; ++ks) {
            const int kb = ks * 64 + lgp * 16;
            bf16x8 af[4], bfr[4];
            #pragma unroll
            for (int m = 0; m < 4; ++m) {
                int row = wr * 64 + m * 16 + l15;
                unsigned byte = ((unsigned)(row * 256 + kb)) ^ ((row & 7) << 4);
                af[m] = *(const bf16x8*)(ldsA + byte);
            }
            #pragma unroll
            for (int n = 0; n < 4; ++n)
                bfr[n] = Wf[((wc * 4 + n) * 4 + ks) * 64 + lane];
            #pragma unroll
            for (int m = 0; m < 4; ++m)
                #pragma unroll
                for (int n = 0; n < 4; ++n)
                    acc[m][n] = __builtin_amdgcn_mfma_f32_16x16x32_bf16(
                        af[m], bfr[n], acc[m][n], 0, 0, 0);
        }
        #pragma unroll
        for (int m = 0; m < 4; ++m)
            #pragma unroll
            for (int j = 0; j < 4; ++j) {
                int row = wr * 64 + m * 16 + lgp * 4 + j;
                size_t e = rowbase + row;
                if (e >= (size_t)M) continue;
                Y[e * 32 + wc * 16 + l15] =
                    make_float4(acc[m][0][j], acc[m][1][j],
                                acc[m][2][j], acc[m][3][j]);
            }
    }
}

// ---------- edge GEMM: EA/logits written at perm position ----------
__global__ __launch_bounds__(256, 4) void edge_gemm(
    const float* __restrict__ X, const bf16x8* __restrict__ Wf,
    const float* __restrict__ bias,
    const float* __restrict__ attw, const float* __restrict__ attb,
    const int* __restrict__ senders, const int* __restrict__ receivers,
    const unsigned* __restrict__ jof,
    const float4* __restrict__ Sp, const float4* __restrict__ Rp,
    uint2* __restrict__ EAp, float* __restrict__ logits)
{
    __shared__ __align__(16) char ldsA[32768];
    __shared__ float sPart[128][4];
    __shared__ int sSnd[128], sRcv[128];
    __shared__ unsigned sJof[128];
    const int t = threadIdx.x;
    const int lane = t & 63;
    const int wid = t >> 6;
    const int wr = wid >> 1, wc = wid & 1;
    const int l15 = lane & 15, lgp = lane >> 4;
    const size_t rowbase = (size_t)blockIdx.x * 128;

    if (t < 128) {
        size_t e = rowbase + t;
        sSnd[t] = senders[e];
        sRcv[t] = receivers[e];
        sJof[t] = jof[e];
    }
    // stage A (NE is a multiple of 128 -> no guards)
    #pragma unroll
    for (int i = 0; i < 8; ++i) {
        int c = i * 256 + t;
        int row = c >> 4, cc = c & 15;
        const float4* src = (const float4*)(X + (rowbase + row) * F + cc * 8);
        float4 f0 = src[0], f1 = src[1];
        uint4 p;
        p.x = f32_to_bf16(f0.x) | (f32_to_bf16(f0.y) << 16);
        p.y = f32_to_bf16(f0.z) | (f32_to_bf16(f0.w) << 16);
        p.z = f32_to_bf16(f1.x) | (f32_to_bf16(f1.y) << 16);
        p.w = f32_to_bf16(f1.z) | (f32_to_bf16(f1.w) << 16);
        unsigned byte = (unsigned)(row * 256 + cc * 16);
        byte ^= (unsigned)((row & 7) << 4);
        *(uint4*)(ldsA + byte) = p;
    }

    f32x4 acc[4][4];
    #pragma unroll
    for (int n = 0; n < 4; ++n) {
        float bv = bias[wc * 64 + n * 16 + l15];
        #pragma unroll
        for (int m = 0; m < 4; ++m) {
            acc[m][n][0] = bv; acc[m][n][1] = bv;
            acc[m][n][2] = bv; acc[m][n][3] = bv;
        }
    }
    __syncthreads();

    #pragma unroll
    for (int ks = 0; ks < 4; ++ks) {
        const int kb = ks * 64 + lgp * 16;
        bf16x8 af[4], bfr[4];
        #pragma unroll
        for (int m = 0; m < 4; ++m) {
            int row = wr * 64 + m * 16 + l15;
            unsigned byte = ((unsigned)(row * 256 + kb)) ^ ((row & 7) << 4);
            af[m] = *(const bf16x8*)(ldsA + byte);
        }
        #pragma unroll
        for (int n = 0; n < 4; ++n)
            bfr[n] = Wf[((wc * 4 + n) * 4 + ks) * 64 + lane];
        #pragma unroll
        for (int m = 0; m < 4; ++m)
            #pragma unroll
            for (int n = 0; n < 4; ++n)
                acc[m][n] = __builtin_amdgcn_mfma_f32_16x16x32_bf16(
                    af[m], bfr[n], acc[m][n], 0, 0, 0);
    }

    const float aw0 = attw[l15];
    const float aw1 = attw[l15 + 16];
    const float ab0 = attb[0];
    #pragma unroll
    for (int m = 0; m < 4; ++m) {
        #pragma unroll
        for (int j2 = 0; j2 < 4; ++j2) {
            int row = wr * 64 + m * 16 + lgp * 4 + j2;
            int snd = sSnd[row];
            int rcv = sRcv[row];
            unsigned jj = sJof[row];
            float4 s4 = Sp[(size_t)snd * 32 + wc * 16 + l15];
            float4 r4 = Rp[(size_t)rcv * 32 + wc * 16 + l15];
            float ea0 = acc[m][0][j2] + s4.x;
            float ea1 = acc[m][1][j2] + s4.y;
            float ea2 = acc[m][2][j2] + s4.z;
            float ea3 = acc[m][3][j2] + s4.w;
            uint2 pk;
            pk.x = f32_to_bf16(ea0) | (f32_to_bf16(ea1) << 16);
            pk.y = f32_to_bf16(ea2) | (f32_to_bf16(ea3) << 16);
            EAp[(size_t)jj * 32 + wc * 16 + l15] = pk;
            float p0 = mish_f(ea0 + r4.x) * aw0 + mish_f(ea1 + r4.y) * aw1;
            float p1 = mish_f(ea2 + r4.z) * aw0 + mish_f(ea3 + r4.w) * aw1;
            p0 += __shfl_xor(p0, 1); p1 += __shfl_xor(p1, 1);
            p0 += __shfl_xor(p0, 2); p1 += __shfl_xor(p1, 2);
            p0 += __shfl_xor(p0, 4); p1 += __shfl_xor(p1, 4);
            p0 += __shfl_xor(p0, 8); p1 += __shfl_xor(p1, 8);
            if (l15 == 0) {
                sPart[row][wc * 2 + 0] = p0 + ab0;
                sPart[row][wc * 2 + 1] = p1 + ab0;
            }
        }
    }
    __syncthreads();
    if (t < 128) {
        unsigned jj = sJof[t];
        float4 lg;
        lg.x = sPart[t][0];
        lg.y = sPart[t][1];
        lg.z = sPart[t][2];
        lg.w = sPart[t][3];
        ((float4*)logits)[jj] = lg;
    }
}

// ---------- fused segment softmax + aggregate (one wave per receiver) ----------
// EA/logits are perm-ordered -> purely sequential segment reads.
__global__ __launch_bounds__(256) void agg_kernel(
    const unsigned* __restrict__ rowptr,
    const float* __restrict__ logits, const unsigned* __restrict__ EA,
    float* __restrict__ out)
{
    const int lane = threadIdx.x & 63;
    const int r = blockIdx.x * 4 + (threadIdx.x >> 6);
    if (r >= NN) return;
    const unsigned start = rowptr[r], end = rowptr[r + 1];
    if (start == end) {
        ((float2*)(out + (size_t)r * HD))[lane] = make_float2(0.f, 0.f);
        return;
    }

    // fragment-permuted EA: uint at index `lane` holds cols c0, c0+16
    const int h  = (lane >> 5) * 2 + (lane & 1);
    const int c0 = (lane >> 5) * 64 + (lane & 1) * 32 + ((lane >> 1) & 15);
    const float NEGBIG = -3.402823466e+38f;

    float4 mx = make_float4(NEGBIG, NEGBIG, NEGBIG, NEGBIG);
    for (unsigned j = start + lane; j < end; j += 64) {
        float4 lg = ((const float4*)logits)[j];
        mx.x = fmaxf(mx.x, lg.x); mx.y = fmaxf(mx.y, lg.y);
        mx.z = fmaxf(mx.z, lg.z); mx.w = fmaxf(mx.w, lg.w);
    }
    #pragma unroll
    for (int o = 1; o < 64; o <<= 1) {
        mx.x = fmaxf(mx.x, __shfl_xor(mx.x, o));
        mx.y = fmaxf(mx.y, __shfl_xor(mx.y, o));
        mx.z = fmaxf(mx.z, __shfl_xor(mx.z, o));
        mx.w = fmaxf(mx.w, __shfl_xor(mx.w, o));
    }
    float4 sm = make_float4(0.f, 0.f, 0.f, 0.f);
    for (unsigned j = start + lane; j < end; j += 64) {
        float4 lg = ((const float4*)logits)[j];
        sm.x += __expf(lg.x - mx.x); sm.y += __expf(lg.y - mx.y);
        sm.z += __expf(lg.z - mx.z); sm.w += __expf(lg.w - mx.w);
    }
    #pragma unroll
    for (int o = 1; o < 64; o <<= 1) {
        sm.x += __shfl_xor(sm.x, o);
        sm.y += __shfl_xor(sm.y, o);
        sm.z += __shfl_xor(sm.z, o);
        sm.w += __shfl_xor(sm.w, o);
    }
    const float mh = (h == 0) ? mx.x : (h == 1) ? mx.y : (h == 2) ? mx.z : mx.w;
    const float sh = (h == 0) ? sm.x : (h == 1) ? sm.y : (h == 2) ? sm.z : sm.w;
    const float rd = 1.f / sh;

    float2 acc = make_float2(0.f, 0.f);
    for (unsigned j = start; j < end; ++j) {
        float lg = logits[(size_t)j * 4 + h];
        float c = __expf(lg - mh) * rd;
        unsigned p = EA[(size_t)j * 64 + lane];
        acc.x += c * bf16lo_to_f32(p);
        acc.y += c * bf16hi_to_f32(p);
    }
    out[(size_t)r * HD + c0]      = acc.x;
    out[(size_t)r * HD + c0 + 16] = acc.y;
}

// ---------- host ----------
extern "C" void kernel_launch(void* const* d_in, const int* in_sizes, int n_in,
                              void* d_out, int out_size, void* d_ws, size_t ws_size,
                              hipStream_t stream) {
    const float* nodes = (const float*)d_in[0];
    const float* edges = (const float*)d_in[1];
    const float* Ws_k  = (const float*)d_in[2];
    const float* Ws_b  = (const float*)d_in[3];
    const float* Wr_k  = (const float*)d_in[4];
    const float* Wr_b  = (const float*)d_in[5];
    const float* We_k  = (const float*)d_in[6];
    const float* We_b  = (const float*)d_in[7];
    const float* attw  = (const float*)d_in[8];
    const float* attb  = (const float*)d_in[9];
    const int* senders   = (const int*)d_in[10];
    const int* receivers = (const int*)d_in[11];
    float* out = (float*)d_out;

    char* ws = (char*)d_ws;
    const size_t CNT_OFF  = 0;            // 200,000
    const size_t CNT2_OFF = 200000;       // 200,000
    const size_t RP_OFF   = 400000;       // 200,004
    const size_t JOF_OFF  = 700000;       // 3,200,000
    const size_t WF_OFF   = 3900008;      // 98,304 (align16: 3900008? no)
    const size_t SP_OFF   = 4100000;      // 25,600,000
    const size_t RPP_OFF  = 29700000;     // 25,600,000
    const size_t LG_OFF   = 55300000;     // 12,800,000
    const size_t EA_OFF   = 68100000;     // 204,800,000  (end 272.9e6)

    unsigned* cnt    = (unsigned*)(ws + CNT_OFF);
    unsigned* cnt2   = (unsigned*)(ws + CNT2_OFF);
    unsigned* rowptr = (unsigned*)(ws + RP_OFF);
    unsigned* jof    = (unsigned*)(ws + JOF_OFF);
    uint4*    Wf     = (uint4*)(ws + WF_OFF - 8);   // 3,900,000 (16B aligned)
    float4*   Sp     = (float4*)(ws + SP_OFF);
    float4*   Rp     = (float4*)(ws + RPP_OFF);
    float*    logits = (float*)(ws + LG_OFF);
    unsigned* EA     = (unsigned*)(ws + EA_OFF);
    (void)ws_size;

    // weights -> bf16 fragment order (Ws, Wr, We)
    prep_w<<<3, 256, 0, stream>>>(Ws_k, Wr_k, We_k, Wf);

    // CSR build (rowptr + inverse perm map jof)
    hipMemsetAsync(ws + CNT_OFF, 0, 400000, stream);   // cnt + cnt2
    hist_kernel<<<(NE + 255) / 256, 256, 0, stream>>>(receivers, cnt);
    scan_kernel<<<1, 1024, 0, stream>>>(cnt, rowptr);
    scatter_kernel<<<(NE + 255) / 256, 256, 0, stream>>>(receivers, rowptr, cnt2, jof);

    // both node projections (fragment-permuted float4 output)
    proj_both<<<(NN + 127) / 128, 256, 0, stream>>>(
        nodes, (const bf16x8*)Wf, (const bf16x8*)(Wf + 2048),
        Ws_b, Wr_b, NN, Sp, Rp);

    // edge GEMM: EA + logits, written at perm positions
    edge_gemm<<<NE / 128, 256, 0, stream>>>(
        edges, (const bf16x8*)(Wf + 4096), We_b,
        attw, attb, senders, receivers, jof, Sp, Rp,
        (uint2*)EA, logits);

    // fused segment softmax + aggregation (sequential segment streams)
    agg_kernel<<<(NN + 3) / 4, 256, 0, stream>>>(rowptr, logits, EA, out);
}